// Round 1
// baseline (4570.395 us; speedup 1.0000x reference)
//
#include <hip/hip_runtime.h>
#include <cmath>

// ---------------------------------------------------------------------------
// MultiSeq2SeqPredict on MI355X: single persistent cooperative kernel.
// R3: remove the 8.4 GB W_out stream from the decode loop.
//  - P1 additionally quantizes W_out to int8 (per-row scale) + exact residual
//    row norms (rigorous screening bound).
//  - Decode Phase L scans the i8 copy (33 MB/step, L2/L3-resident) to find
//    argmax CANDIDATES only; decode_prepare re-checks candidates with the
//    bit-identical fp32 dot (same ldv/dot16/dpp order) -> tokens bit-exact.
//  - Per-step hidden states are archived (F_HALL); logits for all 64 steps
//    are produced once at the end by a weight-stationary GEMM (W_out read
//    ONCE), bit-identical to the old per-step computation.
// Workspace requirement: ~45.2 MB (ctrl 32KB + floats + 32.8MB i8 W_out).
// ---------------------------------------------------------------------------

#define GRID  256
#define TPB   256
#define HD    1024
#define VC    32000
#define LS    64
#define EOS_TOK 1

#define CTRL_BYTES 32768
// float offsets inside workspace (after control block)
#define F_H      0          // 2048  decoder hidden ping-pong [s&1]   [memset 0]
#define F_X      2048       // 1024  decoder GRU input x
#define F_GH     3072       // 3072  dec_W_hh @ h + b_hh (speculative)
#define F_SCH    6144       // 64    W_attn[:,H:] @ h (speculative)
#define F_AW     6208       // 64    attention weights of current step
#define F_PARTV  6272       // 256   per-WG argmax partial values (approx)
#define F_M      6528       // 65536 M = W_comb[:,H:] @ enc_outs^T   [1024][64]
#define F_ENCOUT 72064      // 65536 combined encoder outputs [64][1024]
#define F_GI     137600     // 589824 gi = enc_W_ih@x + b_ih  [3][64][3072]
#define F_OUTS   727424     // 196608 encoder hidden per step [3][64][1024]
#define F_WAE    924032     // 2048000 WaE token-major: [V][64]
#define F_HALL   2972032    // 65536 archived decoder hidden per step [64][1024]
#define F_QSC    3037568    // 32000 per-row i8 scales
#define F_CAND   3069568    // 16384 appended candidates (val,idx) pairs
#define F_WQ     3086336    // (1024-aligned) 32768000 BYTES of i8 W_out [V][1024]
#define CAND_CAP 8192
// total ws bytes = 32768 + (3086336 + 8192000)*4 = 45,146,112  (~45.2 MB)

struct __align__(64) Ctrl {
  int epoch; int _p0[15];
  int arrive[GRID * 16];       // one 64B-padded slot per WG
  int tok; int done; int copy; int candN; int rnmax; int _p1[11];
  int partIdx[GRID];
};

// ---- relaxed system-scope (cache-bypassing, IC-coherent) accessors --------
#define SSC __HIP_MEMORY_SCOPE_SYSTEM
__device__ __forceinline__ int  ld_rlx(const int* p) {
  return __hip_atomic_load(p, __ATOMIC_RELAXED, SSC);
}
__device__ __forceinline__ void st_rlx(int* p, int v) {
  __hip_atomic_store(p, v, __ATOMIC_RELAXED, SSC);
}
__device__ __forceinline__ float ld_f(const float* p) {
  unsigned u = __hip_atomic_load((const unsigned*)p, __ATOMIC_RELAXED, SSC);
  return __builtin_bit_cast(float, u);
}
__device__ __forceinline__ void st_f(float* p, float v) {
  __hip_atomic_store((unsigned*)p, __builtin_bit_cast(unsigned, v), __ATOMIC_RELAXED, SSC);
}
__device__ __forceinline__ float2 ld_f2(const float* p) {
  unsigned long long u =
      __hip_atomic_load((const unsigned long long*)p, __ATOMIC_RELAXED, SSC);
  return __builtin_bit_cast(float2, u);
}
__device__ __forceinline__ void st_f2(float* p, float2 v) {
  __hip_atomic_store((unsigned long long*)p,
                     __builtin_bit_cast(unsigned long long, v),
                     __ATOMIC_RELAXED, SSC);
}
__device__ __forceinline__ void st_u64(void* p, unsigned long long v) {
  __hip_atomic_store((unsigned long long*)p, v, __ATOMIC_RELAXED, SSC);
}

typedef struct { float4 v[4]; } V16;   // one wave covers 1024 floats

__device__ __forceinline__ V16 ldv(const float* __restrict__ p, int lane) {
  V16 r;
#pragma unroll
  for (int c = 0; c < 4; ++c)
    r.v[c] = *(const float4*)(p + c * 256 + lane * 4);
  return r;
}

// uncached variant (same values/order; for fb data written via st_f)
__device__ __forceinline__ V16 ldv_u(const float* p, int lane) {
  V16 r;
#pragma unroll
  for (int c = 0; c < 4; ++c) {
    float2 a = ld_f2(p + c * 256 + lane * 4);
    float2 b = ld_f2(p + c * 256 + lane * 4 + 2);
    r.v[c] = make_float4(a.x, a.y, b.x, b.y);
  }
  return r;
}

__device__ __forceinline__ float dot16(const V16& a, const V16& b) {
  float s = 0.f;
#pragma unroll
  for (int c = 0; c < 4; ++c) {
    s = fmaf(a.v[c].x, b.v[c].x, s);
    s = fmaf(a.v[c].y, b.v[c].y, s);
    s = fmaf(a.v[c].z, b.v[c].z, s);
    s = fmaf(a.v[c].w, b.v[c].w, s);
  }
  return s;
}

// int8 dot: q bytes pair with permuted-layout h fragments
__device__ __forceinline__ float idot4(unsigned u, float4 h, float s) {
  s = fmaf((float)(int)(signed char)(u & 255u), h.x, s);
  s = fmaf((float)(int)(signed char)((u >> 8) & 255u), h.y, s);
  s = fmaf((float)(int)(signed char)((u >> 16) & 255u), h.z, s);
  s = fmaf((float)(int)(signed char)(u >> 24), h.w, s);
  return s;
}
__device__ __forceinline__ float idot16(const uint4 q, const V16& h) {
  float s = 0.f;
  s = idot4(q.x, h.v[0], s);
  s = idot4(q.y, h.v[1], s);
  s = idot4(q.z, h.v[2], s);
  s = idot4(q.w, h.v[3], s);
  return s;
}

// DPP wave64 reductions on the VALU pipe; full result lands in lane 63.
template <int DCTL>
__device__ __forceinline__ float dppadd(float v) {
  int t = __builtin_amdgcn_update_dpp(0, __builtin_bit_cast(int, v), DCTL, 0xF, 0xF, true);
  return v + __builtin_bit_cast(float, t);
}
__device__ __forceinline__ float dpp_sum63(float v) {
  v = dppadd<0x111>(v);
  v = dppadd<0x112>(v);
  v = dppadd<0x114>(v);
  v = dppadd<0x118>(v);
  v = dppadd<0x142>(v);
  v = dppadd<0x143>(v);
  return v;
}
template <int DCTL>
__device__ __forceinline__ float dppmax_(float v) {   // inputs must be >= 0
  int t = __builtin_amdgcn_update_dpp(0, __builtin_bit_cast(int, v), DCTL, 0xF, 0xF, true);
  return fmaxf(v, __builtin_bit_cast(float, t));
}
__device__ __forceinline__ float dpp_max63(float v) {
  v = dppmax_<0x111>(v);
  v = dppmax_<0x112>(v);
  v = dppmax_<0x114>(v);
  v = dppmax_<0x118>(v);
  v = dppmax_<0x142>(v);
  v = dppmax_<0x143>(v);
  return v;
}
__device__ __forceinline__ float bcast63(float v) {
  return __builtin_bit_cast(float,
      __builtin_amdgcn_readlane(__builtin_bit_cast(int, v), 63));
}

__device__ __forceinline__ float sumsq4(float4 a) {
  return fmaf(a.x, a.x, fmaf(a.y, a.y, fmaf(a.z, a.z, a.w * a.w)));
}
// deterministic block reduction (identical op order everywhere it is used)
__device__ __forceinline__ float block_sum256(float v, float* s_red, int tid) {
  s_red[tid] = v; __syncthreads();
  for (int st = TPB / 2; st > 0; st >>= 1) {
    if (tid < st) s_red[tid] += s_red[tid + st];
    __syncthreads();
  }
  float r = s_red[0]; __syncthreads();
  return r;
}

__device__ __forceinline__ float gru_out(float gir, float giz, float gin,
                                         float ghr, float ghz, float ghn, float hp) {
  float r = 1.f / (1.f + expf(-(gir + ghr)));
  float z = 1.f / (1.f + expf(-(giz + ghz)));
  float n = tanhf(gin + r * ghn);
  return (1.f - z) * n + z * hp;
}

// ---- fence-free slotted grid barrier --------------------------------------
__device__ __forceinline__ void bar_worker(Ctrl* c, int t) {
  __syncthreads();                       // compiler drains vmcnt before s_barrier
  if (threadIdx.x == 0) {
    __builtin_amdgcn_s_waitcnt(0);       // belt-and-suspenders for this wave
    st_rlx(&c->arrive[blockIdx.x * 16], t);
    while (ld_rlx(&c->epoch) < t) __builtin_amdgcn_s_sleep(4);
  }
  __syncthreads();
}
__device__ __forceinline__ void bar_master_wait(Ctrl* c, int t) {
  __syncthreads();
  if (threadIdx.x > 0) {                 // thread i watches WG i's slot
    while (ld_rlx(&c->arrive[threadIdx.x * 16]) < t) __builtin_amdgcn_s_sleep(1);
  }
  __syncthreads();
}
__device__ __forceinline__ void bar_master_release(Ctrl* c, int t) {
  __syncthreads();                       // drains master's serial-stage stores
  if (threadIdx.x == 0) {
    __builtin_amdgcn_s_waitcnt(0);
    st_rlx(&c->epoch, t);
  }
  __syncthreads();
}

// ---- serial per-step stage, run by WG0 inside the barrier (prepares step s).
__device__ void decode_prepare(int s, Ctrl* c, float* __restrict__ fb,
                               const float* __restrict__ b_attn,
                               const float* __restrict__ Wout,
                               const float* __restrict__ bout,
                               float* __restrict__ out_attns,
                               float* __restrict__ out_toks) {
  const int tid = threadIdx.x;
  __shared__ float s_v[TPB];
  __shared__ int   s_ci[1024];
  __shared__ float s_cv[1024];
  __shared__ int   s_cn;
  int frozen = 0;
  if (s > 0) {
    int done_entry = ld_rlx(&c->done);   // state at entry of step s-1
    if (!done_entry) {
      // ---- global approx max over 256 WG partials
      float pv = ld_f(fb + F_PARTV + tid);
      s_v[tid] = pv; __syncthreads();
      for (int st = TPB / 2; st > 0; st >>= 1) {
        if (tid < st) s_v[tid] = fmaxf(s_v[tid], s_v[tid + st]);
        __syncthreads();
      }
      float gmax = s_v[0];
      // ---- ||h|| and screening window (identical code path to phase L's)
      const float* hb = fb + F_H + (s & 1) * HD;
      float2 ha = ld_f2(hb + tid * 4);
      float2 hc = ld_f2(hb + tid * 4 + 2);
      float4 h4 = make_float4(ha.x, ha.y, hc.x, hc.y);
      __syncthreads();
      float ssq = block_sum256(sumsq4(h4), s_v, tid);
      float hn = sqrtf(ssq) * 1.00001f;
      float rmx = __int_as_float(ld_rlx(&c->rnmax));
      float Wp = fmaf(2.0f * rmx, hn, 4e-6f * (1.0f + hn));
      float T = gmax - Wp;
      // ---- collect candidate rows (approx >= T covers all possible winners)
      if (tid == 0) s_cn = 0;
      __syncthreads();
      if (pv >= T) {
        int k = atomicAdd(&s_cn, 1);
        if (k < 1024) s_ci[k] = ld_rlx(&c->partIdx[tid]);
      }
      int nap = ld_rlx(&c->candN); if (nap > CAND_CAP) nap = CAND_CAP;
      for (int k2 = tid; k2 < nap; k2 += TPB) {
        float av = ld_f(fb + F_CAND + 2 * k2);
        if (av >= T) {
          int k = atomicAdd(&s_cn, 1);
          if (k < 1024) s_ci[k] = ld_rlx((int*)(fb + F_CAND) + 2 * k2 + 1);
        }
      }
      __syncthreads();
      int m = s_cn; if (m > 1024) m = 1024;
      // ---- exact fp32 re-check (bit-identical op order to reference kernel)
      {
        int pw = tid >> 6, pl = tid & 63;
        V16 hvv = ldv_u(hb, pl);
        for (int k = pw; k < m; k += 4) {
          int row = s_ci[k];
          V16 w = ldv(Wout + (size_t)row * HD, pl);
          float ex = bcast63(dpp_sum63(dot16(w, hvv))) + bout[row];
          if (pl == 0) s_cv[k] = ex;
        }
      }
      __syncthreads();
      if (tid == 0) {
        float bv = s_cv[0]; int bi = s_ci[0];
        for (int k = 1; k < m; ++k)
          if (s_cv[k] > bv || (s_cv[k] == bv && s_ci[k] < bi)) { bv = s_cv[k]; bi = s_ci[k]; }
        out_toks[s - 1] = (float)bi;
        st_rlx(&c->tok, bi);
        if (bi == EOS_TOK) st_rlx(&c->done, 1);
        st_rlx(&c->candN, 0);
      }
    } else {
      // fully frozen: outputs of step s are copies of step s-1
      frozen = 1;
      if (tid == 0) { out_toks[s - 1] = (float)ld_rlx(&c->tok); st_rlx(&c->copy, 1); }
      if (s < LS) {
        if (tid < LS) out_attns[s * LS + tid] = out_attns[(s - 1) * LS + tid];
#pragma unroll
        for (int k2 = 0; k2 < 4; ++k2) {   // hall[s] = hall[s-1] for final GEMM
          int i = k2 * 256 + tid;
          st_f(fb + F_HALL + (size_t)s * HD + i,
               ld_f(fb + F_HALL + (size_t)(s - 1) * HD + i));
        }
      }
    }
  }
  if (s >= LS || frozen) return;
  __syncthreads();
  int tok = ld_rlx(&c->tok);
  if (tid < LS) {   // wave 0: scores -> softmax -> aw  (WaE is token-major)
    float sc = fb[F_WAE + (size_t)tok * LS + tid] + ld_f(fb + F_SCH + tid) + b_attn[tid];
    float m = sc;
    for (int off = 32; off > 0; off >>= 1) m = fmaxf(m, __shfl_xor(m, off, 64));
    float ex = expf(sc - m);
    float sum = ex;
    for (int off = 32; off > 0; off >>= 1) sum += __shfl_xor(sum, off, 64);
    float a = ex / sum;
    st_f(fb + F_AW + tid, a);
    out_attns[s * LS + tid] = a;
  }
}

__global__ void __launch_bounds__(TPB, 1)
seq2seq_kernel(const int* __restrict__ qids, const int* __restrict__ cand,
               const float* __restrict__ enc_emb, const float* __restrict__ enc_Wih,
               const float* __restrict__ enc_Whh, const float* __restrict__ enc_bih,
               const float* __restrict__ enc_bhh, const float* __restrict__ dec_emb,
               const float* __restrict__ W_attn, const float* __restrict__ b_attn,
               const float* __restrict__ W_comb, const float* __restrict__ b_comb,
               const float* __restrict__ dWih, const float* __restrict__ dWhh,
               const float* __restrict__ dbih, const float* __restrict__ dbhh,
               const float* __restrict__ Wout, const float* __restrict__ bout,
               float* __restrict__ out, float* __restrict__ ws) {
  Ctrl* c = (Ctrl*)ws;
  float* fb = (float*)((char*)ws + CTRL_BYTES);
  const int tid = threadIdx.x;
  const int wg = blockIdx.x;
  const int wid = tid >> 6;
  const int lane = tid & 63;
  float* out_attns = out + (size_t)LS * VC;
  float* out_toks = out_attns + LS * LS;
  int bt = 0;

  __shared__ float s_h[3][HD];     // P2: staged h_{t-1} per encoder
  __shared__ float s_vec[HD];      // decode: staged x (G) / h2 (L, standard)
  __shared__ float s_vecp[HD];     // decode: staged h2 (permuted for i8 dot)
  __shared__ float s_red[TPB];
  __shared__ float s_apx[128];
  __shared__ float s_lv[4]; __shared__ int s_li[4];
  __shared__ float s_bbv; __shared__ int s_bbi;

#define GRID_BARRIER() do { ++bt; \
    if (wg == 0) { bar_master_wait(c, bt); bar_master_release(c, bt); } \
    else bar_worker(c, bt); } while (0)

  // ==== P1: gi GEMM (3 encoders) + WaE precompute + W_out i8 quantization ===
  {
    int gw = wg * 4 + wid;
    float lrmax = 0.f;
#pragma unroll 1
    for (int task = gw; task < 2304 + 2 * VC; task += GRID * 4) {
      if (task < 2304) {   // 4 rows of enc_W_ih x 64 timesteps
        int r0 = task * 4;
        int e = r0 / 3072;
        int rL = r0 - e * 3072;
        const float* Wr = enc_Wih + (size_t)e * 3 * HD * HD + (size_t)rL * HD;
        V16 w0 = ldv(Wr, lane), w1 = ldv(Wr + HD, lane);
        V16 w2 = ldv(Wr + 2 * HD, lane), w3 = ldv(Wr + 3 * HD, lane);
        const int* ids = (e == 0) ? qids : (cand + (e - 1) * LS);
        float b0 = enc_bih[e * 3 * HD + rL + 0];
        float b1 = enc_bih[e * 3 * HD + rL + 1];
        float b2 = enc_bih[e * 3 * HD + rL + 2];
        float b3 = enc_bih[e * 3 * HD + rL + 3];
#pragma unroll 1
        for (int t = 0; t < LS; ++t) {
          int tk = ids[t];
          V16 xv = ldv(enc_emb + ((size_t)e * VC + tk) * HD, lane);
          float s0 = dpp_sum63(dot16(w0, xv));
          float s1 = dpp_sum63(dot16(w1, xv));
          float s2 = dpp_sum63(dot16(w2, xv));
          float s3 = dpp_sum63(dot16(w3, xv));
          if (lane == 63) {
            float* dst = fb + F_GI + (size_t)(e * LS + t) * 3 * HD + rL;
            st_f2(dst, make_float2(s0 + b0, s1 + b1));
            st_f2(dst + 2, make_float2(s2 + b2, s3 + b3));
          }
        }
      } else if (task < 2304 + VC) {   // WaE row (token-major) for one token
        int cc = task - 2304;
        V16 ev = ldv(dec_emb + (size_t)cc * HD, lane);
        float myval = 0.f;
#pragma unroll 1
        for (int k = 0; k < LS; k += 4) {
          float a0 = dot16(ldv(W_attn + (size_t)(k + 0) * 2 * HD, lane), ev);
          float a1 = dot16(ldv(W_attn + (size_t)(k + 1) * 2 * HD, lane), ev);
          float a2 = dot16(ldv(W_attn + (size_t)(k + 2) * 2 * HD, lane), ev);
          float a3 = dot16(ldv(W_attn + (size_t)(k + 3) * 2 * HD, lane), ev);
          a0 = bcast63(dpp_sum63(a0));
          a1 = bcast63(dpp_sum63(a1));
          a2 = bcast63(dpp_sum63(a2));
          a3 = bcast63(dpp_sum63(a3));
          myval = (lane == k + 0) ? a0 : myval;
          myval = (lane == k + 1) ? a1 : myval;
          myval = (lane == k + 2) ? a2 : myval;
          myval = (lane == k + 3) ? a3 : myval;
        }
        st_f(fb + F_WAE + (size_t)cc * LS + lane, myval);   // coalesced 256B
      } else {             // quantize one W_out row to i8 + exact resid norm
        int r = task - (2304 + VC);
        const float* wl = Wout + (size_t)r * HD + lane * 16;
        float4 a0 = *(const float4*)(wl);
        float4 a1 = *(const float4*)(wl + 4);
        float4 a2 = *(const float4*)(wl + 8);
        float4 a3 = *(const float4*)(wl + 12);
        float mx = fmaxf(
            fmaxf(fmaxf(fabsf(a0.x), fabsf(a0.y)), fmaxf(fabsf(a0.z), fabsf(a0.w))),
            fmaxf(fmaxf(fabsf(a1.x), fabsf(a1.y)), fmaxf(fabsf(a1.z), fabsf(a1.w))));
        mx = fmaxf(mx, fmaxf(
            fmaxf(fmaxf(fabsf(a2.x), fabsf(a2.y)), fmaxf(fabsf(a2.z), fabsf(a2.w))),
            fmaxf(fmaxf(fabsf(a3.x), fabsf(a3.y)), fmaxf(fabsf(a3.z), fabsf(a3.w)))));
        mx = bcast63(dpp_max63(mx));
        float scale = fmaxf(mx, 1e-30f) * (1.0f / 127.0f);
        float inv = 1.0f / scale;
        float r2 = 0.f;
        unsigned wq0, wq1, wq2, wq3;
#pragma unroll
        for (int cq = 0; cq < 4; ++cq) {
          float4 aa = (cq == 0) ? a0 : (cq == 1) ? a1 : (cq == 2) ? a2 : a3;
          int q0 = __float2int_rn(aa.x * inv); q0 = q0 > 127 ? 127 : (q0 < -127 ? -127 : q0);
          int q1 = __float2int_rn(aa.y * inv); q1 = q1 > 127 ? 127 : (q1 < -127 ? -127 : q1);
          int q2 = __float2int_rn(aa.z * inv); q2 = q2 > 127 ? 127 : (q2 < -127 ? -127 : q2);
          int q3 = __float2int_rn(aa.w * inv); q3 = q3 > 127 ? 127 : (q3 < -127 ? -127 : q3);
          float d;
          d = fmaf(-scale, (float)q0, aa.x); r2 = fmaf(d, d, r2);
          d = fmaf(-scale, (float)q1, aa.y); r2 = fmaf(d, d, r2);
          d = fmaf(-scale, (float)q2, aa.z); r2 = fmaf(d, d, r2);
          d = fmaf(-scale, (float)q3, aa.w); r2 = fmaf(d, d, r2);
          unsigned w = (unsigned)(q0 & 255) | ((unsigned)(q1 & 255) << 8) |
                       ((unsigned)(q2 & 255) << 16) | ((unsigned)(q3 & 255) << 24);
          if (cq == 0) wq0 = w; else if (cq == 1) wq1 = w; else if (cq == 2) wq2 = w; else wq3 = w;
        }
        float r2s = bcast63(dpp_sum63(r2));
        char* qrow = (char*)(fb + F_WQ) + (size_t)r * 1024 + lane * 16;
        st_u64(qrow, (unsigned long long)wq0 | ((unsigned long long)wq1 << 32));
        st_u64(qrow + 8, (unsigned long long)wq2 | ((unsigned long long)wq3 << 32));
        if (lane == 0) st_f(fb + F_QSC + r, scale);
        lrmax = fmaxf(lrmax, sqrtf(r2s));
      }
    }
    if (lane == 0) atomicMax(&c->rnmax, __float_as_int(lrmax));
  }
  GRID_BARRIER();

  // ================= P2: encoder recurrence (64 steps, 3 encoders) ==========
#pragma unroll 1
  for (int t = 0; t < LS; ++t) {
    // stage h_{t-1} of all 3 encoders into LDS (sc-bypass reads)
#pragma unroll
    for (int k2 = 0; k2 < 6; ++k2) {
      int off = k2 * 256 + tid;          // float2 index in [0,1536)
      int e = off >> 9, rem = off & 511;
      float2 v = make_float2(0.f, 0.f);
      if (t > 0) v = ld_f2(fb + F_OUTS + (size_t)(e * LS + (t - 1)) * HD + rem * 2);
      *(float2*)&s_h[e][rem * 2] = v;
    }
    __syncthreads();
    int j = wg * 4 + wid;                // 1024 waves <-> hidden index j
#pragma unroll 1
    for (int e = 0; e < 3; ++e) {
      const float* Whh = enc_Whh + (size_t)e * 3 * HD * HD;
      V16 hv = ldv(&s_h[e][0], lane);
      float ghr = dpp_sum63(dot16(ldv(Whh + (size_t)j * HD, lane), hv));
      float ghz = dpp_sum63(dot16(ldv(Whh + (size_t)(HD + j) * HD, lane), hv));
      float ghn = dpp_sum63(dot16(ldv(Whh + (size_t)(2 * HD + j) * HD, lane), hv));
      if (lane == 63) {
        ghr += enc_bhh[e * 3 * HD + j];
        ghz += enc_bhh[e * 3 * HD + HD + j];
        ghn += enc_bhh[e * 3 * HD + 2 * HD + j];
        const float* gi = fb + F_GI + (size_t)(e * LS + t) * 3 * HD;
        float hp = s_h[e][j];
        st_f(fb + F_OUTS + (size_t)(e * LS + t) * HD + j,
             gru_out(gi[j], gi[HD + j], gi[2 * HD + j], ghr, ghz, ghn, hp));
      }
    }
    GRID_BARRIER();
  }

  // ===== P2b1: combine encoder outputs; init gh=b_hh, scoresH=0 =============
  {
    int gt = wg * TPB + tid;   // 0..65535
    float o0 = fb[F_OUTS + gt];
    float o1 = fb[F_OUTS + 65536 + gt];
    float o2 = fb[F_OUTS + 131072 + gt];
    st_f(fb + F_ENCOUT + gt, o0 + 0.5f * (o1 + o2));
    if (gt < 3 * HD) st_f(fb + F_GH + gt, dbhh[gt]);   // W_hh @ 0 + b_hh
    if (gt < LS) st_f(fb + F_SCH + gt, 0.f);           // W_attn[:,H:] @ 0
  }
  GRID_BARRIER();

  // ===== P2b2: M = W_comb[:, H:] @ enc_outs^T  (then prepare step 0) ========
  {
    int r = wg * 4 + wid;
    V16 wr = ldv(W_comb + (size_t)r * 2 * HD + HD, lane);
#pragma unroll 1
    for (int t = 0; t < LS; ++t) {
      float s = dpp_sum63(dot16(wr, ldv(fb + F_ENCOUT + (size_t)t * HD, lane)));
      if (lane == 63) st_f(fb + F_M + r * LS + t, s);
    }
  }
  ++bt;
  if (wg == 0) { bar_master_wait(c, bt); decode_prepare(0, c, fb, b_attn, Wout, bout, out_attns, out_toks); bar_master_release(c, bt); }
  else bar_worker(c, bt);

  // ================= decode: 64 steps, 3 barriers each ======================
#pragma unroll 1
  for (int s = 0; s < LS; ++s) {
    int cp = ld_rlx(&c->copy);
    const int hcur = F_H + (s & 1) * HD;
    const int hnew = F_H + ((s + 1) & 1) * HD;

    // ---- Phase X: x = relu(W_comb[:, :H] @ e + M @ aw + b_comb)
    if (!cp) {
      int tok = ld_rlx(&c->tok);
      int r = wg * 4 + wid;
      V16 ev = ldv(dec_emb + (size_t)tok * HD, lane);
      V16 wr = ldv(W_comb + (size_t)r * 2 * HD, lane);
      float p = dot16(wr, ev);
      if (lane < 16) {
        float4 m4 = *(const float4*)(fb + F_M + r * LS + lane * 4);
        float2 a01 = ld_f2(fb + F_AW + lane * 4);
        float2 a23 = ld_f2(fb + F_AW + lane * 4 + 2);
        p = fmaf(m4.x, a01.x, p); p = fmaf(m4.y, a01.y, p);
        p = fmaf(m4.z, a23.x, p); p = fmaf(m4.w, a23.y, p);
      }
      float sum = dpp_sum63(p);
      if (lane == 63) st_f(fb + F_X + r, fmaxf(sum + b_comb[r], 0.f));
    }
    GRID_BARRIER();

    // ---- Phase G: gi = dec_W_ih @ x; h_new = GRU(h_cur, x); archive h_new
    if (!cp) {
#pragma unroll
      for (int k2 = 0; k2 < 2; ++k2) {     // stage x into LDS
        int off = k2 * 256 + tid;
        *(float2*)&s_vec[off * 2] = ld_f2(fb + F_X + off * 2);
      }
      __syncthreads();
      int j = wg * 4 + wid;
      V16 xv = ldv(s_vec, lane);
      float g0 = dpp_sum63(dot16(ldv(dWih + (size_t)j * HD, lane), xv));
      float g1 = dpp_sum63(dot16(ldv(dWih + (size_t)(HD + j) * HD, lane), xv));
      float g2 = dpp_sum63(dot16(ldv(dWih + (size_t)(2 * HD + j) * HD, lane), xv));
      if (lane == 63) {
        g0 += dbih[j]; g1 += dbih[HD + j]; g2 += dbih[2 * HD + j];
        float ghr = ld_f(fb + F_GH + j);
        float ghz = ld_f(fb + F_GH + HD + j);
        float ghn = ld_f(fb + F_GH + 2 * HD + j);
        float hp = ld_f(fb + hcur + j);
        float hval = gru_out(g0, g1, g2, ghr, ghz, ghn, hp);
        st_f(fb + hnew + j, hval);
        st_f(fb + F_HALL + (size_t)s * HD + j, hval);
      }
      __syncthreads();
    }
    GRID_BARRIER();

    // ---- Phase L: i8 approx vocab scan (argmax screening) + speculative gh
    if (!cp) {
#pragma unroll
      for (int k2 = 0; k2 < 2; ++k2) {     // stage h2 (standard layout)
        int off = k2 * 256 + tid;
        *(float2*)&s_vec[off * 2] = ld_f2(fb + hnew + off * 2);
      }
      {                                    // stage h2 (permuted, i8 layout)
        int cI = tid >> 6, lI = tid & 63;
        float2 pa = ld_f2(fb + hnew + lI * 16 + cI * 4);
        float2 pb = ld_f2(fb + hnew + lI * 16 + cI * 4 + 2);
        *(float4*)&s_vecp[cI * 256 + lI * 4] = make_float4(pa.x, pa.y, pb.x, pb.y);
      }
      __syncthreads();
      float4 hh4 = *(const float4*)&s_vec[tid * 4];
      float ssq = block_sum256(sumsq4(hh4), s_red, tid);
      float hn = sqrtf(ssq) * 1.00001f;
      float rmx = __int_as_float(ld_rlx(&c->rnmax));
      float Wp = fmaf(2.0f * rmx, hn, 4e-6f * (1.0f + hn));
      float Wwork = Wp * 1.5f + 1e-7f;     // strictly >= prepare's window
      V16 hv = ldv(s_vec, lane);
      for (int q = wid; q < 12; q += 4) {  // speculative dec_W_hh @ h2 + b_hh
        int row = wg * 12 + q;
        float g = dpp_sum63(dot16(ldv(dWhh + (size_t)row * HD, lane), hv));
        if (lane == 63) st_f(fb + F_GH + row, g + dbhh[row]);
      }
      if (wg < LS && wid == 0) {           // speculative W_attn[:,H:] @ h2
        float g = dpp_sum63(dot16(ldv(W_attn + (size_t)wg * 2 * HD + HD, lane), hv));
        if (lane == 63) st_f(fb + F_SCH + wg, g);
      }
      // i8 scan over this WG's 125 vocab rows (cached loads: L2-resident)
      V16 hq = ldv(s_vecp, lane);
      const unsigned char* qb = (const unsigned char*)(fb + F_WQ);
      int base = wg * 125;
      int lo = wid * 32;
      int hi = (lo + 32 < 125) ? lo + 32 : 125;
      float bestv = -3.0e38f; int bestr = 0x7FFFFFFF;
#pragma unroll 1
      for (int rr = lo; rr < hi; rr += 4) {
        int i1 = (rr + 1 < hi) ? rr + 1 : hi - 1;
        int i2 = (rr + 2 < hi) ? rr + 2 : hi - 1;
        int i3 = (rr + 3 < hi) ? rr + 3 : hi - 1;
        int r0 = base + rr, r1 = base + i1, r2 = base + i2, r3 = base + i3;
        uint4 q0 = *(const uint4*)(qb + (size_t)r0 * 1024 + lane * 16);
        uint4 q1 = *(const uint4*)(qb + (size_t)r1 * 1024 + lane * 16);
        uint4 q2 = *(const uint4*)(qb + (size_t)r2 * 1024 + lane * 16);
        uint4 q3 = *(const uint4*)(qb + (size_t)r3 * 1024 + lane * 16);
        float p0 = idot16(q0, hq), p1 = idot16(q1, hq);
        float p2 = idot16(q2, hq), p3 = idot16(q3, hq);
        float v0 = bcast63(dpp_sum63(p0)) * fb[F_QSC + r0] + bout[r0];
        float v1 = bcast63(dpp_sum63(p1)) * fb[F_QSC + r1] + bout[r1];
        float v2 = bcast63(dpp_sum63(p2)) * fb[F_QSC + r2] + bout[r2];
        float v3 = bcast63(dpp_sum63(p3)) * fb[F_QSC + r3] + bout[r3];
        float sv = (lane == 0) ? v0 : (lane == 1) ? v1 : (lane == 2) ? v2 : v3;
        if (lane < 4 && rr + lane < hi) s_apx[rr + lane] = sv;
        if (v0 > bestv) { bestv = v0; bestr = r0; }
        if (v1 > bestv) { bestv = v1; bestr = r1; }
        if (v2 > bestv) { bestv = v2; bestr = r2; }
        if (v3 > bestv) { bestv = v3; bestr = r3; }
      }
      if (lane == 0) { s_lv[wid] = bestv; s_li[wid] = bestr; }
      __syncthreads();
      if (tid == 0) {
        float bv = s_lv[0]; int bi = s_li[0];
#pragma unroll
        for (int q2 = 1; q2 < 4; ++q2)
          if (s_lv[q2] > bv || (s_lv[q2] == bv && s_li[q2] < bi)) { bv = s_lv[q2]; bi = s_li[q2]; }
        s_bbv = bv; s_bbi = bi;
        st_f(fb + F_PARTV + wg, bv);
        st_rlx(&c->partIdx[wg], bi);
      }
      __syncthreads();
      if (tid < 125) {                     // append near-local-max rows
        float a = s_apx[tid];
        if (base + tid != s_bbi && a >= s_bbv - Wwork) {
          int n = atomicAdd(&c->candN, 1);
          if (n < CAND_CAP) {
            st_f(fb + F_CAND + 2 * n, a);
            st_rlx((int*)(fb + F_CAND) + 2 * n + 1, base + tid);
          }
        }
      }
    }
    ++bt;
    if (wg == 0) { bar_master_wait(c, bt); decode_prepare(s + 1, c, fb, b_attn, Wout, bout, out_attns, out_toks); bar_master_release(c, bt); }
    else bar_worker(c, bt);
  }

  // ===== P3: logits GEMM from archived h (W_out fp32 read ONCE) =============
  {
    int base2 = wg * 125;
#pragma unroll 1
    for (int gg = wid; gg < 16; gg += 4) {
      int rr = gg * 8;
      int e1 = rr + 1 < 125 ? rr + 1 : 124;
      int e2 = rr + 2 < 125 ? rr + 2 : 124;
      int e3 = rr + 3 < 125 ? rr + 3 : 124;
      int e4 = rr + 4 < 125 ? rr + 4 : 124;
      int e5 = rr + 5 < 125 ? rr + 5 : 124;
      int e6 = rr + 6 < 125 ? rr + 6 : 124;
      int e7 = rr + 7 < 125 ? rr + 7 : 124;
      V16 w0 = ldv(Wout + (size_t)(base2 + rr) * HD, lane);
      V16 w1 = ldv(Wout + (size_t)(base2 + e1) * HD, lane);
      V16 w2 = ldv(Wout + (size_t)(base2 + e2) * HD, lane);
      V16 w3 = ldv(Wout + (size_t)(base2 + e3) * HD, lane);
      V16 w4 = ldv(Wout + (size_t)(base2 + e4) * HD, lane);
      V16 w5 = ldv(Wout + (size_t)(base2 + e5) * HD, lane);
      V16 w6 = ldv(Wout + (size_t)(base2 + e6) * HD, lane);
      V16 w7 = ldv(Wout + (size_t)(base2 + e7) * HD, lane);
      float b0 = bout[base2 + rr], b1 = bout[base2 + e1];
      float b2 = bout[base2 + e2], b3 = bout[base2 + e3];
      float b4 = bout[base2 + e4], b5 = bout[base2 + e5];
      float b6 = bout[base2 + e6], b7 = bout[base2 + e7];
#pragma unroll 1
      for (int s2 = 0; s2 < LS; ++s2) {
        V16 hvv = ldv(fb + F_HALL + (size_t)s2 * HD, lane);
        float v0 = bcast63(dpp_sum63(dot16(w0, hvv))) + b0;
        float v1 = bcast63(dpp_sum63(dot16(w1, hvv))) + b1;
        float v2 = bcast63(dpp_sum63(dot16(w2, hvv))) + b2;
        float v3 = bcast63(dpp_sum63(dot16(w3, hvv))) + b3;
        float v4 = bcast63(dpp_sum63(dot16(w4, hvv))) + b4;
        float v5 = bcast63(dpp_sum63(dot16(w5, hvv))) + b5;
        float v6 = bcast63(dpp_sum63(dot16(w6, hvv))) + b6;
        float v7 = bcast63(dpp_sum63(dot16(w7, hvv))) + b7;
        float sv = v0;
        sv = (lane == 1) ? v1 : sv;
        sv = (lane == 2) ? v2 : sv;
        sv = (lane == 3) ? v3 : sv;
        sv = (lane == 4) ? v4 : sv;
        sv = (lane == 5) ? v5 : sv;
        sv = (lane == 6) ? v6 : sv;
        sv = (lane == 7) ? v7 : sv;
        if (lane < 8 && rr + lane < 125)
          st_f(out + (size_t)s2 * VC + base2 + rr + lane, sv);
      }
    }
  }
  GRID_BARRIER();

  // ================= P4: in-place log_softmax per step row ==================
  if (wg < LS) {
    float* row = out + (size_t)wg * VC;
    float m = -3.0e38f;
    for (int i = tid; i < VC; i += TPB) m = fmaxf(m, row[i]);
    s_red[tid] = m; __syncthreads();
    for (int st = TPB / 2; st > 0; st >>= 1) {
      if (tid < st) s_red[tid] = fmaxf(s_red[tid], s_red[tid + st]);
      __syncthreads();
    }
    float rowmax = s_red[0]; __syncthreads();
    float sum = 0.f;
    for (int i = tid; i < VC; i += TPB) sum += expf(row[i] - rowmax);
    s_red[tid] = sum; __syncthreads();
    for (int st = TPB / 2; st > 0; st >>= 1) {
      if (tid < st) s_red[tid] += s_red[tid + st];
      __syncthreads();
    }
    float lse = rowmax + logf(s_red[0]);
    __syncthreads();
    for (int i = tid; i < VC; i += TPB) row[i] -= lse;
  }
}

extern "C" void kernel_launch(void* const* d_in, const int* in_sizes, int n_in,
                              void* d_out, int out_size, void* d_ws, size_t ws_size,
                              hipStream_t stream) {
  (void)in_sizes; (void)n_in; (void)out_size; (void)ws_size;
  // zero barrier state + both decoder hidden buffers (first 2048 floats of fb)
  hipMemsetAsync(d_ws, 0, CTRL_BYTES + 2 * HD * sizeof(float), stream);

  const int* qids = (const int*)d_in[0];
  const int* cand = (const int*)d_in[1];
  const float* enc_emb = (const float*)d_in[2];
  const float* enc_Wih = (const float*)d_in[3];
  const float* enc_Whh = (const float*)d_in[4];
  const float* enc_bih = (const float*)d_in[5];
  const float* enc_bhh = (const float*)d_in[6];
  const float* dec_emb = (const float*)d_in[7];
  const float* W_attn = (const float*)d_in[8];
  const float* b_attn = (const float*)d_in[9];
  const float* W_comb = (const float*)d_in[10];
  const float* b_comb = (const float*)d_in[11];
  const float* dWih = (const float*)d_in[12];
  const float* dWhh = (const float*)d_in[13];
  const float* dbih = (const float*)d_in[14];
  const float* dbhh = (const float*)d_in[15];
  const float* Wout = (const float*)d_in[16];
  const float* bout = (const float*)d_in[17];
  float* outp = (float*)d_out;
  float* wsp = (float*)d_ws;

  void* args[] = { &qids, &cand, &enc_emb, &enc_Wih, &enc_Whh, &enc_bih, &enc_bhh,
                   &dec_emb, &W_attn, &b_attn, &W_comb, &b_comb, &dWih, &dWhh,
                   &dbih, &dbhh, &Wout, &bout, &outp, &wsp };
  hipLaunchCooperativeKernel(reinterpret_cast<void*>(seq2seq_kernel),
                             dim3(GRID), dim3(TPB), args, 0, stream);
}